// Round 1
// baseline (261.176 us; speedup 1.0000x reference)
//
#include <hip/hip_runtime.h>
#include <math.h>

// Problem: x fp32 [B=8, C=64, D=32, H=128, W=128]
//   norm over C, avg+max over spatial, relu, sigmoid(out^2) -> [B,C]
#define NC   64
#define NS   524288            // 32*128*128 spatial positions per (b,c)
#define NB   8
#define P    256               // spatial positions per chunk
#define PAD  257               // LDS row stride (conflict-free: bank=(c+p)%32)
#define BPB  256               // blocks per batch
#define CHUNKS_PER_BLK ((NS / P) / BPB)   // 2048/256 = 8

// Phase 1: stream 64 channels of a P-position chunk into LDS (coalesced),
//          accumulating per-position norm^2 in registers.
// Phase 2: channel-major re-read from LDS, accumulate per-channel sum/max.
// Partials per block -> d_ws (no atomics, fully rewritten every launch).
__global__ __launch_bounds__(256, 2)
void ca_partial(const float* __restrict__ x, float* __restrict__ ws) {
    __shared__ float x_s[NC][PAD];
    __shared__ float rnorm_s[P];
    __shared__ float part_sum[4][NC];
    __shared__ float part_max[4][NC];

    const int b   = blockIdx.y;
    const int blk = blockIdx.x;
    const int t   = threadIdx.x;
    const int c2  = t & 63;    // phase-2 channel (lane)
    const int g   = t >> 6;    // phase-2 position group (wave id)

    float run_sum = 0.0f;
    float run_max = -INFINITY;

    const float* xb = x + (size_t)b * NC * NS;

    for (int ch = 0; ch < CHUNKS_PER_BLK; ++ch) {
        const int s0 = (blk * CHUNKS_PER_BLK + ch) * P;

        // ---- phase 1: global -> LDS, norm^2 accumulation ----
        const float* p0 = xb + s0 + t;
        float nsq = 0.0f;
        #pragma unroll 16
        for (int c = 0; c < NC; ++c) {
            float v = p0[(size_t)c * NS];     // coalesced 4B/lane
            x_s[c][t] = v;
            nsq = fmaf(v, v, nsq);
        }
        rnorm_s[t] = 1.0f / fmaxf(sqrtf(nsq), 1e-12f);
        __syncthreads();                      // A: x_s + rnorm visible

        // ---- phase 2: LDS -> per-channel partial sum/max ----
        float psum = 0.0f, pmax = -INFINITY;
        #pragma unroll 8
        for (int i = 0; i < P / 4; ++i) {
            int p = (g << 6) + i;             // wave g scans positions g*64..g*64+63
            float xn = x_s[c2][p] * rnorm_s[p];   // rnorm broadcast (same p per wave)
            psum += xn;
            pmax = fmaxf(pmax, xn);
        }
        part_sum[g][c2] = psum;
        part_max[g][c2] = pmax;
        __syncthreads();                      // B: partials visible, x_s reads done

        if (t < NC) {                         // wave 0 accumulates (before next A)
            run_sum += part_sum[0][t] + part_sum[1][t]
                     + part_sum[2][t] + part_sum[3][t];
            float m01 = fmaxf(part_max[0][t], part_max[1][t]);
            float m23 = fmaxf(part_max[2][t], part_max[3][t]);
            run_max = fmaxf(run_max, fmaxf(m01, m23));
        }
    }

    if (t < NC) {
        float* w = ws + (size_t)(b * BPB + blk) * (2 * NC);
        w[t]      = run_sum;
        w[NC + t] = run_max;
    }
}

// Reduce BPB partials per (b,c), apply relu + sigmoid(out^2).
__global__ __launch_bounds__(256)
void ca_final(const float* __restrict__ ws, float* __restrict__ out) {
    __shared__ float fs[4][NC];
    __shared__ float fm[4][NC];

    const int b = blockIdx.x;          // 0..7
    const int t = threadIdx.x;         // 256
    const int c = t & 63;
    const int q = t >> 6;

    float s = 0.0f, m = -INFINITY;
    for (int blk = q; blk < BPB; blk += 4) {
        const float* w = ws + (size_t)(b * BPB + blk) * (2 * NC);
        s += w[c];                     // coalesced (lane = c)
        m = fmaxf(m, w[NC + c]);
    }
    fs[q][c] = s;
    fm[q][c] = m;
    __syncthreads();

    if (t < NC) {
        float ts = fs[0][t] + fs[1][t] + fs[2][t] + fs[3][t];
        float tm = fmaxf(fmaxf(fm[0][t], fm[1][t]), fmaxf(fm[2][t], fm[3][t]));
        float avg = ts * (1.0f / (float)NS);
        float o   = fmaxf(avg + tm, 0.0f);
        float att = 1.0f / (1.0f + expf(-o * o));
        out[b * NC + t] = att;
    }
}

extern "C" void kernel_launch(void* const* d_in, const int* in_sizes, int n_in,
                              void* d_out, int out_size, void* d_ws, size_t ws_size,
                              hipStream_t stream) {
    const float* x = (const float*)d_in[0];
    float* ws  = (float*)d_ws;
    float* out = (float*)d_out;

    dim3 grid1(BPB, NB);
    ca_partial<<<grid1, 256, 0, stream>>>(x, ws);
    ca_final<<<NB, 256, 0, stream>>>(ws, out);
}

// Round 2
// 228.772 us; speedup vs baseline: 1.1416x; 1.1416x over previous
//
#include <hip/hip_runtime.h>
#include <math.h>

// x fp32 [B=8, C=64, S=32*128*128=524288]
// norm over C, avg+max over S, relu, sigmoid(out^2) -> [B,C]
#define NC   64
#define NS   524288
#define NB   8
#define BPB  256               // blocks per batch
#define CHUNK 8                // chunks per block
#define P    256               // positions per chunk (64 lanes x float4)

// Register-resident design: wave w owns channels {4i+w}, lane k owns
// positions 4k..4k+3 of each chunk. x is loaded ONCE as float4 and held in
// 64 VGPRs across the norm reduction; only nsq goes through LDS (8KB,
// parity double-buffered -> one barrier per chunk). No x staging, no
// transpose, no bank conflicts.
__global__ __launch_bounds__(256, 3)
void ca_partial(const float* __restrict__ x, float* __restrict__ ws) {
    __shared__ float nsq_s[2][4][P];

    const int b   = blockIdx.y;
    const int blk = blockIdx.x;
    const int t   = threadIdx.x;
    const int w   = t >> 6;     // wave id 0..3
    const int k   = t & 63;     // lane

    float run_sum[16], run_max[16];
    #pragma unroll
    for (int i = 0; i < 16; ++i) { run_sum[i] = 0.0f; run_max[i] = -INFINITY; }

    const float* xb = x + (size_t)b * NC * NS;

    for (int ch = 0; ch < CHUNK; ++ch) {
        const int s0 = (blk * CHUNK + ch) * P;
        const float* pbase = xb + s0 + 4 * k;

        // ---- load 16 channels x float4, accumulate per-position norm^2 ----
        float4 v[16];
        float nx = 0.f, ny = 0.f, nz = 0.f, nw = 0.f;
        #pragma unroll
        for (int i = 0; i < 16; ++i) {
            v[i] = *reinterpret_cast<const float4*>(pbase + (size_t)(4 * i + w) * NS);
            nx = fmaf(v[i].x, v[i].x, nx);
            ny = fmaf(v[i].y, v[i].y, ny);
            nz = fmaf(v[i].z, v[i].z, nz);
            nw = fmaf(v[i].w, v[i].w, nw);
        }

        // ---- cross-wave nsq reduce via LDS (parity buffer, 1 barrier) ----
        const int par = ch & 1;
        float4* row = reinterpret_cast<float4*>(&nsq_s[par][w][4 * k]);
        *row = make_float4(nx, ny, nz, nw);
        __syncthreads();

        const float4 q0 = *reinterpret_cast<const float4*>(&nsq_s[par][0][4 * k]);
        const float4 q1 = *reinterpret_cast<const float4*>(&nsq_s[par][1][4 * k]);
        const float4 q2 = *reinterpret_cast<const float4*>(&nsq_s[par][2][4 * k]);
        const float4 q3 = *reinterpret_cast<const float4*>(&nsq_s[par][3][4 * k]);
        const float tx = q0.x + q1.x + q2.x + q3.x;
        const float ty = q0.y + q1.y + q2.y + q3.y;
        const float tz = q0.z + q1.z + q2.z + q3.z;
        const float tw = q0.w + q1.w + q2.w + q3.w;

        const float rx = 1.0f / fmaxf(sqrtf(tx), 1e-12f);
        const float ry = 1.0f / fmaxf(sqrtf(ty), 1e-12f);
        const float rz = 1.0f / fmaxf(sqrtf(tz), 1e-12f);
        const float rw = 1.0f / fmaxf(sqrtf(tw), 1e-12f);

        // ---- normalize held registers, accumulate per-channel sum/max ----
        #pragma unroll
        for (int i = 0; i < 16; ++i) {
            run_sum[i] = fmaf(v[i].x, rx, run_sum[i]);
            run_sum[i] = fmaf(v[i].y, ry, run_sum[i]);
            run_sum[i] = fmaf(v[i].z, rz, run_sum[i]);
            run_sum[i] = fmaf(v[i].w, rw, run_sum[i]);
            const float m0 = fmaxf(v[i].x * rx, v[i].y * ry);
            const float m1 = fmaxf(v[i].z * rz, v[i].w * rw);
            run_max[i] = fmaxf(run_max[i], fmaxf(m0, m1));
        }
    }

    // ---- one-time wave butterfly reduce, lane 0 writes partials ----
    float* wp = ws + (size_t)(b * BPB + blk) * (2 * NC);
    #pragma unroll
    for (int i = 0; i < 16; ++i) {
        float s = run_sum[i];
        float m = run_max[i];
        #pragma unroll
        for (int d = 32; d > 0; d >>= 1) {
            s += __shfl_xor(s, d, 64);
            m = fmaxf(m, __shfl_xor(m, d, 64));
        }
        if (k == 0) {
            wp[4 * i + w]      = s;   // channel c = 4i+w
            wp[NC + 4 * i + w] = m;
        }
    }
}

// Reduce BPB partials per (b,c), apply relu + sigmoid(out^2).
__global__ __launch_bounds__(256)
void ca_final(const float* __restrict__ ws, float* __restrict__ out) {
    __shared__ float fs[4][NC];
    __shared__ float fm[4][NC];

    const int b = blockIdx.x;
    const int t = threadIdx.x;
    const int c = t & 63;
    const int q = t >> 6;

    float s = 0.0f, m = -INFINITY;
    for (int blk = q; blk < BPB; blk += 4) {
        const float* w = ws + (size_t)(b * BPB + blk) * (2 * NC);
        s += w[c];
        m = fmaxf(m, w[NC + c]);
    }
    fs[q][c] = s;
    fm[q][c] = m;
    __syncthreads();

    if (t < NC) {
        float ts = fs[0][t] + fs[1][t] + fs[2][t] + fs[3][t];
        float tm = fmaxf(fmaxf(fm[0][t], fm[1][t]), fmaxf(fm[2][t], fm[3][t]));
        float avg = ts * (1.0f / (float)NS);
        float o   = fmaxf(avg + tm, 0.0f);
        float att = 1.0f / (1.0f + expf(-o * o));
        out[b * NC + t] = att;
    }
}

extern "C" void kernel_launch(void* const* d_in, const int* in_sizes, int n_in,
                              void* d_out, int out_size, void* d_ws, size_t ws_size,
                              hipStream_t stream) {
    const float* x = (const float*)d_in[0];
    float* ws  = (float*)d_ws;
    float* out = (float*)d_out;

    dim3 grid1(BPB, NB);
    ca_partial<<<grid1, 256, 0, stream>>>(x, ws);
    ca_final<<<NB, 256, 0, stream>>>(ws, out);
}